// Round 8
// baseline (4420.795 us; speedup 1.0000x reference)
//
#include <hip/hip_runtime.h>
#include <cstdint>
#include <cstddef>

#define B_  64
#define T_  512
#define I_  256
#define H_  1024
#define O_  10
#define ZST 68              // zpart row stride (f32)
#define ZPW (64 * ZST)      // per-wave partial block (floats)
#define ZBUF (4 * ZPW)      // per-parity zpart buffer (floats)
#define LDS_ALLOC 139264    // 2 x 4 x 64 x 68 x 4 B (double-buffered zpart), 1 block/CU

typedef __attribute__((ext_vector_type(4))) float f32x4;
typedef __attribute__((ext_vector_type(8))) short s16x8;
typedef unsigned long long u64;

__device__ inline unsigned short f2bf(float f) {
    unsigned int u = __float_as_uint(f);
    u += 0x7fffu + ((u >> 16) & 1u);     // round-to-nearest-even
    return (unsigned short)(u >> 16);
}
__device__ inline float bf2f(unsigned short h) {
    return __uint_as_float(((unsigned int)h) << 16);
}
__device__ inline float fsig(float x)  { return 1.0f / (1.0f + __expf(-x)); }
__device__ inline float ftanh(float x) { return 1.0f - 2.0f / (1.0f + __expf(2.0f * x)); }

#define ALD32(p)    __hip_atomic_load((p), __ATOMIC_RELAXED, __HIP_MEMORY_SCOPE_AGENT)
#define AST32(p, v) __hip_atomic_store((p), (v), __ATOMIC_RELAXED, __HIP_MEMORY_SCOPE_AGENT)
#define ALD64(p)    __hip_atomic_load((p), __ATOMIC_RELAXED, __HIP_MEMORY_SCOPE_AGENT)
#define AST64(p, v) __hip_atomic_store((p), (v), __ATOMIC_RELAXED, __HIP_MEMORY_SCOPE_AGENT)
// NOTE (R2-R4 lesson): NO __ATOMIC_RELEASE at agent scope in the hot loop — gfx950
// emits a per-publish L2 writeback. Publish = s_waitcnt vmcnt(0) + relaxed flag.
// R7: consumer h loads are PLAIN cached loads behind an ACQUIRE fence (buffer_inv):
// sc1 loads bypass L2, so the 8 blocks/XCD each re-pulled the full 128 KB h from L3
// every step (8 MB/step chip-wide). Cached loads + one inv share the fills via L2.
// __hip_atomic_fence doesn't exist in this ROCm; use the clang builtin.
#define ACQ_FENCE() __builtin_amdgcn_fence(__ATOMIC_ACQUIRE, "agent")

// Pin a 128-bit fragment into the AGPR file (opaque volatile def: not remat-able,
// zero VGPR pressure; MFMA reads operands from AGPRs directly).
#define PIN_A(x) asm volatile("" : "+a"(x))

// ---------------------------------------------------------------- prolog packs
// xb[t][b][i] (bf16)  <-  x[b][t][i] (fp32)
__global__ __launch_bounds__(256) void cast_xT_kernel(const float* __restrict__ x,
                                                      unsigned short* __restrict__ xb) {
    int idx = blockIdx.x * 256 + threadIdx.x;          // 2,097,152 ushort4 items
    int ic4 = idx & 63, rest = idx >> 6;
    int t = rest & 511, b = rest >> 9;
    float4 v = ((const float4*)x)[((size_t)(b * T_ + t)) * 64 + ic4];
    ((ushort4*)xb)[((size_t)(t * B_ + b)) * 64 + ic4] =
        make_ushort4(f2bf(v.x), f2bf(v.y), f2bf(v.z), f2bf(v.w));
}

// Pack Wh into MFMA B-fragments: e = nb*8192 + kt*256 + nt*64 + lane.
__global__ __launch_bounds__(256) void pack_wh_kernel(const float* __restrict__ Wh,
                                                      uint4* __restrict__ whp) {
    int e = blockIdx.x * 256 + threadIdx.x;            // 524,288
    int lane = e & 63, nt = (e >> 6) & 3, kt = (e >> 8) & 31, nb = e >> 13;
    int q = (lane & 15) >> 2, cc = lane & 3;
    int hh = nb * 16 + nt * 4 + cc;
    int k0 = kt * 32 + (lane >> 4) * 8;
    const float* src = Wh + (size_t)q * (H_ * H_) + (size_t)k0 * H_ + hh;
    unsigned short u[8];
#pragma unroll
    for (int j = 0; j < 8; ++j) u[j] = f2bf(src[(size_t)j * H_]);
    uint4 out;
    out.x = (unsigned)u[0] | ((unsigned)u[1] << 16);
    out.y = (unsigned)u[2] | ((unsigned)u[3] << 16);
    out.z = (unsigned)u[4] | ((unsigned)u[5] << 16);
    out.w = (unsigned)u[6] | ((unsigned)u[7] << 16);
    whp[e] = out;
}

// Same fragment pack for Wx (K = 256 -> 8 kt).
__global__ __launch_bounds__(256) void pack_wx_kernel(const float* __restrict__ Wx,
                                                      uint4* __restrict__ wxp) {
    int e = blockIdx.x * 256 + threadIdx.x;            // 131,072
    int lane = e & 63, nt = (e >> 6) & 3, kt = (e >> 8) & 7, nb = e >> 11;
    int q = (lane & 15) >> 2, cc = lane & 3;
    int hh = nb * 16 + nt * 4 + cc;
    int i0 = kt * 32 + (lane >> 4) * 8;
    const float* src = Wx + (size_t)q * (I_ * H_) + (size_t)i0 * H_ + hh;
    unsigned short u[8];
#pragma unroll
    for (int j = 0; j < 8; ++j) u[j] = f2bf(src[(size_t)j * H_]);
    uint4 out;
    out.x = (unsigned)u[0] | ((unsigned)u[1] << 16);
    out.y = (unsigned)u[2] | ((unsigned)u[3] << 16);
    out.z = (unsigned)u[4] | ((unsigned)u[5] << 16);
    out.w = (unsigned)u[6] | ((unsigned)u[7] << 16);
    wxp[e] = out;
}

// ---------------------------------------------------------------- persistent LSTM
// Blocks 0..63: LSTM (block nb owns h-cols [nb*16,+16), K-split across 4 waves).
// Blocks 64..255: VALU warmers. flags[nb*4+w] = # published h states.
// h ring: 4 buffers (16384 u64). Step t reads buf[t&3], writes buf[(t+1)&3].
// Exchange protocol: producer sc1-stores h + vmcnt(0) + relaxed flag (data at L3
// when flag visible). Consumer: poll flags -> acquire fence (buffer_inv: drops
// stale L1/L2 lines) -> PLAIN uint4 loads (L2-cached, shared across the XCD).
// WAR on ring slot t&3 is safe: writer of h(t+3) polls flags>=t+3 from ALL blocks,
// which implies every block finished step t+2, long past reading buf[t&3].
__global__ __launch_bounds__(256, 1) void lstm_kernel(const unsigned short* __restrict__ xb,
                                                      const uint4* __restrict__ whp,
                                                      const uint4* __restrict__ wxp,
                                                      const float* __restrict__ bx,
                                                      const float* __restrict__ bh,
                                                      const float* __restrict__ Wp,
                                                      const float* __restrict__ bp,
                                                      unsigned short* __restrict__ hbuf,
                                                      unsigned int* __restrict__ flags,
                                                      float* __restrict__ out) {
    extern __shared__ float zpart[];     // [2][4][64][ZST] = 139,264 B (double-buffered)
    int tid = threadIdx.x, lane = tid & 63, w = tid >> 6;
    int nb = blockIdx.x;
    unsigned int* done = flags + 768;    // byte offset 3072, separate line

    if (nb >= 64) {
        // ---- warmer: dependent-FMA spin to hold the power state up
        float a = 1.0f + (float)tid * 0.001f;
        const float bm = 1.0000001f, cm = 0.9999999f;
        while (ALD32(done) == 0u) {
#pragma unroll
            for (int i = 0; i < 512; ++i) a = __builtin_fmaf(a, bm, cm);
        }
        if (__float_as_uint(a) == 0xDEADBEEFu) AST32(&flags[200], 1u);  // sink
        return;
    }

    int ma = lane & 15, quad = lane >> 4;

    // resident weight fragments (B-operands), pinned into AGPRs
    const s16x8* whpp = (const s16x8*)whp;
    const s16x8* wxpp = (const s16x8*)wxp;
    s16x8 whf[4][8], wxf[4][2];
#pragma unroll
    for (int nt = 0; nt < 4; ++nt) {
#pragma unroll
        for (int k = 0; k < 8; ++k)
            whf[nt][k] = whpp[nb * 8192 + (w * 8 + k) * 256 + nt * 64 + lane];
#pragma unroll
        for (int k = 0; k < 2; ++k)
            wxf[nt][k] = wxpp[nb * 2048 + (w * 2 + k) * 256 + nt * 64 + lane];
    }
#pragma unroll
    for (int nt = 0; nt < 4; ++nt) {
#pragma unroll
        for (int k = 0; k < 8; ++k) PIN_A(whf[nt][k]);
#pragma unroll
        for (int k = 0; k < 2; ++k) PIN_A(wxf[nt][k]);
    }

    // gate-stage ownership: thread (gb, wq) -> batch gb, h-cols nb*16+wq*4..+4
    int gb = tid >> 2, wq = tid & 3;
    float bias[4][4];
#pragma unroll
    for (int g = 0; g < 4; ++g)
#pragma unroll
        for (int i = 0; i < 4; ++i) {
            int n = g * H_ + nb * 16 + wq * 4 + i;
            bias[g][i] = bx[n] + bh[n];
        }

    u64* hbase = (u64*)hbuf;             // 4 buffers x 16384 u64

    // h(-1)=0 init into buf 0 (wave's own 512 B slice) + per-wave publish
    AST64(&hbase[nb * 256 + tid], 0ull);
    asm volatile("s_waitcnt vmcnt(0)" ::: "memory");
    if (lane == 0) AST32(&flags[nb * 4 + w], 1u);

    float cst[4] = {0.f, 0.f, 0.f, 0.f};

    for (int t = 0; t < T_; ++t) {
        // ---- x fragments: independent of other blocks
        s16x8 Ax[4][2];
#pragma unroll
        for (int mt = 0; mt < 4; ++mt) {
            const unsigned short* xrow =
                xb + ((size_t)t * B_ + mt * 16 + ma) * I_ + w * 64 + quad * 8;
            Ax[mt][0] = *(const s16x8*)xrow;
            Ax[mt][1] = *(const s16x8*)(xrow + 32);
        }

        // ---- x-projection MFMAs BEFORE the poll (no cross-block dependence)
        f32x4 acc[4][4] = {};
#pragma unroll
        for (int mt = 0; mt < 4; ++mt)
#pragma unroll
            for (int kx = 0; kx < 2; ++kx)
#pragma unroll
                for (int nt = 0; nt < 4; ++nt)
                    acc[mt][nt] = __builtin_amdgcn_mfma_f32_16x16x32_bf16(Ax[mt][kx], wxf[nt][kx],
                                                                          acc[mt][nt], 0, 0, 0);
        __builtin_amdgcn_sched_barrier(0);   // keep the x-cluster ahead of the poll

        // ---- per-wave poll of this wave's 16 producers (4 wave-flags each)
        {
            unsigned tgt = (unsigned)(t + 1);
            for (;;) {
                unsigned v = ALD32(&flags[w * 64 + lane]);
                if (__ballot(v < tgt) == 0ull) break;
                __builtin_amdgcn_s_sleep(1);
            }
        }

        // ---- acquire fence: buffer_inv drops stale L1/L2 h lines; after it,
        //      plain cached loads observe the L3 (coherence-point) data the
        //      flags vouch for.
        ACQ_FENCE();

        const uint4* hp4 = (const uint4*)(hbase + (size_t)(t & 3) * 16384);  // h(t-1)
        u64*         hn  = hbase + (size_t)((t + 1) & 3) * 16384;            // h(t)

        // ---- PLAIN vectorized h loads: 32 x 16 B per lane, L2-cacheable ->
        //      the 8 blocks of an XCD share one set of L3 fills.
        uint4 Ah4[4][8];
#pragma unroll
        for (int mt = 0; mt < 4; ++mt) {
            int row = mt * 16 + ma;
#pragma unroll
            for (int kl = 0; kl < 8; ++kl) {
                Ah4[mt][kl] = hp4[((size_t)((w * 8 + kl) * 2 + (quad >> 1))) * 128
                                  + (size_t)row * 2 + (quad & 1)];
            }
        }

#pragma unroll
        for (int mt = 0; mt < 4; ++mt) {
#pragma unroll
            for (int kl = 0; kl < 8; ++kl) {
                union { uint4 u4; s16x8 v; } au;
                au.u4 = Ah4[mt][kl];
#pragma unroll
                for (int nt = 0; nt < 4; ++nt)
                    acc[mt][nt] = __builtin_amdgcn_mfma_f32_16x16x32_bf16(au.v, whf[nt][kl],
                                                                          acc[mt][nt], 0, 0, 0);
            }
        }

        // ---- write partial to LDS (parity-selected buffer; safe under 1-barrier drift)
        float* zb = zpart + (size_t)(t & 1) * ZBUF;
        float* zp = zb + w * ZPW;
#pragma unroll
        for (int mt = 0; mt < 4; ++mt)
#pragma unroll
            for (int nt = 0; nt < 4; ++nt)
#pragma unroll
                for (int r = 0; r < 4; ++r)
                    zp[(mt * 16 + quad * 4 + r) * ZST + nt * 16 + ma] = acc[mt][nt][r];
        __syncthreads();                 // the ONLY barrier per step (partials complete)

        // ---- gates: sum 4 partials, z col = wq*16 + g*4 + i
        float zs[4][4];
#pragma unroll
        for (int g = 0; g < 4; ++g) {
            float4 s = make_float4(0.f, 0.f, 0.f, 0.f);
#pragma unroll
            for (int p = 0; p < 4; ++p) {
                float4 v = *(const float4*)(zb + p * ZPW + gb * ZST + wq * 16 + g * 4);
                s.x += v.x; s.y += v.y; s.z += v.z; s.w += v.w;
            }
            zs[g][0] = s.x; zs[g][1] = s.y; zs[g][2] = s.z; zs[g][3] = s.w;
        }
        unsigned short hh[4];
#pragma unroll
        for (int i = 0; i < 4; ++i) {
            float g  = ftanh(zs[0][i] + bias[0][i]);
            float ii = fsig (zs[1][i] + bias[1][i]);
            float ff = fsig (zs[2][i] + bias[2][i]);
            float oo = fsig (zs[3][i] + bias[3][i]);
            float c  = g * ii + cst[i] * ff;
            cst[i] = c;
            hh[i] = f2bf(ftanh(c) * oo);
        }
        u64 hv = (u64)hh[0] | ((u64)hh[1] << 16) | ((u64)hh[2] << 32) | ((u64)hh[3] << 48);
        AST64(&hn[nb * 256 + tid], hv);  // sc1 store: data goes to the coherence point

        // ---- per-wave publish: own stores drained -> own flag (R1/R5 form)
        asm volatile("s_waitcnt vmcnt(0)" ::: "memory");
        if (lane == 0) AST32(&flags[nb * 4 + w], (unsigned)(t + 2));
    }

    // final wait: all 256 wave-flags at T+1
    {
        unsigned tgt = (unsigned)(T_ + 1);
        for (;;) {
            unsigned v = ALD32(&flags[w * 64 + lane]);
            if (__ballot(v < tgt) == 0ull) break;
            __builtin_amdgcn_s_sleep(1);
        }
    }
    __syncthreads();
    if (nb == 0 && tid == 0) AST32(done, 1u);   // release warmers

    // ---------------- projection + softmax: block nb handles batch row nb
    int b = nb;
    union { u64 q; unsigned short s[4]; } hu;
    hu.q = ALD64(&hbase[(tid >> 2) * 256 + b * 4 + (tid & 3)]);   // h(T-1) -> buf 0 (sc1)
    int j0 = (tid >> 2) * 16 + (tid & 3) * 4;
    float pacc[O_];
#pragma unroll
    for (int o = 0; o < O_; ++o) pacc[o] = 0.f;
#pragma unroll
    for (int j = 0; j < 4; ++j) {
        float hvv = bf2f(hu.s[j]);
        const float* wr = Wp + (size_t)(j0 + j) * O_;
#pragma unroll
        for (int o = 0; o < O_; ++o) pacc[o] += hvv * wr[o];
    }
    float* red = zpart;
#pragma unroll
    for (int o = 0; o < O_; ++o) red[tid * O_ + o] = pacc[o];
    __syncthreads();
    for (int s2 = 128; s2 > 0; s2 >>= 1) {
        if (tid < s2) {
#pragma unroll
            for (int o = 0; o < O_; ++o) red[tid * O_ + o] += red[(tid + s2) * O_ + o];
        }
        __syncthreads();
    }
    if (tid == 0) {
        float p[O_];
        for (int o = 0; o < O_; ++o) p[o] = red[o] + bp[o];
        float mx = p[0];
        for (int o = 1; o < O_; ++o) mx = fmaxf(mx, p[o]);
        float e[O_], sum = 0.f;
        for (int o = 0; o < O_; ++o) { e[o] = __expf(p[o] - mx); sum += e[o]; }
        float inv = 1.f / sum;
        for (int o = 0; o < O_; ++o) out[b * O_ + o] = e[o] * inv;
    }
}

// ---------------------------------------------------------------- launch
extern "C" void kernel_launch(void* const* d_in, const int* in_sizes, int n_in,
                              void* d_out, int out_size, void* d_ws, size_t ws_size,
                              hipStream_t stream) {
    (void)in_sizes; (void)n_in; (void)out_size; (void)ws_size;
    const float* x  = (const float*)d_in[0];
    const float* Wx = (const float*)d_in[1];
    const float* bx = (const float*)d_in[2];
    const float* Wh = (const float*)d_in[3];
    const float* bh = (const float*)d_in[4];
    const float* Wp = (const float*)d_in[5];
    const float* bp = (const float*)d_in[6];

    const size_t xbB  = (size_t)T_ * B_ * I_ * 2;      // 16 MB
    const size_t whpB = (size_t)4 * H_ * H_ * 2;       // 8 MB
    const size_t wxpB = (size_t)4 * I_ * H_ * 2;       // 2 MB
    const size_t hB   = (size_t)4 * B_ * H_ * 2;       // 512 KB (4-deep ring)

    char* ws = (char*)d_ws;
    unsigned short* xb    = (unsigned short*)ws;
    uint4*          whp   = (uint4*)(ws + xbB);
    uint4*          wxp   = (uint4*)(ws + xbB + whpB);
    unsigned short* hbuf  = (unsigned short*)(ws + xbB + whpB + wxpB);
    unsigned int*   flags = (unsigned int*)(ws + xbB + whpB + wxpB + hB);

    static bool attr_set = false;
    if (!attr_set) {
        (void)hipFuncSetAttribute((const void*)lstm_kernel,
                                  hipFuncAttributeMaxDynamicSharedMemorySize, LDS_ALLOC);
        attr_set = true;
    }

    hipError_t e0 = hipMemsetAsync(flags, 0, 4096, stream);
    (void)e0;
    cast_xT_kernel<<<8192, 256, 0, stream>>>(x, xb);
    pack_wh_kernel<<<2048, 256, 0, stream>>>(Wh, whp);
    pack_wx_kernel<<< 512, 256, 0, stream>>>(Wx, wxp);
    lstm_kernel<<<64 + 192, 256, LDS_ALLOC, stream>>>(xb, whp, wxp, bx, bh, Wp, bp, hbuf, flags,
                                                      (float*)d_out);
}

// Round 9
// 3721.984 us; speedup vs baseline: 1.1878x; 1.1878x over previous
//
#include <hip/hip_runtime.h>
#include <cstdint>
#include <cstddef>

#define B_  64
#define T_  512
#define I_  256
#define H_  1024
#define O_  10
#define ZST 68              // zpart row stride (f32)
#define ZPW (64 * ZST)      // per-wave partial block (floats)
#define ZBUF (4 * ZPW)      // per-parity zpart buffer (floats)
#define LDS_ALLOC 139264    // 2 x 4 x 64 x 68 x 4 B (double-buffered zpart), 1 block/CU

typedef __attribute__((ext_vector_type(4))) float f32x4;
typedef __attribute__((ext_vector_type(8))) short s16x8;
typedef unsigned long long u64;

__device__ inline unsigned short f2bf(float f) {
    unsigned int u = __float_as_uint(f);
    u += 0x7fffu + ((u >> 16) & 1u);     // round-to-nearest-even
    return (unsigned short)(u >> 16);
}
__device__ inline float bf2f(unsigned short h) {
    return __uint_as_float(((unsigned int)h) << 16);
}
__device__ inline float fsig(float x)  { return 1.0f / (1.0f + __expf(-x)); }
__device__ inline float ftanh(float x) { return 1.0f - 2.0f / (1.0f + __expf(2.0f * x)); }

#define ALD32(p)    __hip_atomic_load((p), __ATOMIC_RELAXED, __HIP_MEMORY_SCOPE_AGENT)
#define AST32(p, v) __hip_atomic_store((p), (v), __ATOMIC_RELAXED, __HIP_MEMORY_SCOPE_AGENT)
#define ALD64(p)    __hip_atomic_load((p), __ATOMIC_RELAXED, __HIP_MEMORY_SCOPE_AGENT)
#define AST64(p, v) __hip_atomic_store((p), (v), __ATOMIC_RELAXED, __HIP_MEMORY_SCOPE_AGENT)
// Lessons ledger:
//  R2-R4: NO __ATOMIC_RELEASE at agent scope per step (L2 writeback, +2.3 us/step).
//  R8:    NO per-step acquire fence / cached h loads (buffer_inv empties the XCD L2;
//         xb re-fills cost more than shared h fills save; +0.59 us/step).
// Publish = s_waitcnt vmcnt(0) + relaxed flag store; consume = sc1 (L2-bypass) loads.

// Pin a 128-bit fragment into the AGPR file (opaque volatile def: not remat-able,
// zero VGPR pressure; MFMA reads operands from AGPRs directly).
#define PIN_A(x) asm volatile("" : "+a"(x))

// ---------------------------------------------------------------- prolog packs
// xb[t][b][i] (bf16)  <-  x[b][t][i] (fp32)
__global__ __launch_bounds__(256) void cast_xT_kernel(const float* __restrict__ x,
                                                      unsigned short* __restrict__ xb) {
    int idx = blockIdx.x * 256 + threadIdx.x;          // 2,097,152 ushort4 items
    int ic4 = idx & 63, rest = idx >> 6;
    int t = rest & 511, b = rest >> 9;
    float4 v = ((const float4*)x)[((size_t)(b * T_ + t)) * 64 + ic4];
    ((ushort4*)xb)[((size_t)(t * B_ + b)) * 64 + ic4] =
        make_ushort4(f2bf(v.x), f2bf(v.y), f2bf(v.z), f2bf(v.w));
}

// Pack Wh into MFMA B-fragments: e = nb*8192 + kt*256 + nt*64 + lane.
__global__ __launch_bounds__(256) void pack_wh_kernel(const float* __restrict__ Wh,
                                                      uint4* __restrict__ whp) {
    int e = blockIdx.x * 256 + threadIdx.x;            // 524,288
    int lane = e & 63, nt = (e >> 6) & 3, kt = (e >> 8) & 31, nb = e >> 13;
    int q = (lane & 15) >> 2, cc = lane & 3;
    int hh = nb * 16 + nt * 4 + cc;
    int k0 = kt * 32 + (lane >> 4) * 8;
    const float* src = Wh + (size_t)q * (H_ * H_) + (size_t)k0 * H_ + hh;
    unsigned short u[8];
#pragma unroll
    for (int j = 0; j < 8; ++j) u[j] = f2bf(src[(size_t)j * H_]);
    uint4 out;
    out.x = (unsigned)u[0] | ((unsigned)u[1] << 16);
    out.y = (unsigned)u[2] | ((unsigned)u[3] << 16);
    out.z = (unsigned)u[4] | ((unsigned)u[5] << 16);
    out.w = (unsigned)u[6] | ((unsigned)u[7] << 16);
    whp[e] = out;
}

// Same fragment pack for Wx (K = 256 -> 8 kt).
__global__ __launch_bounds__(256) void pack_wx_kernel(const float* __restrict__ Wx,
                                                      uint4* __restrict__ wxp) {
    int e = blockIdx.x * 256 + threadIdx.x;            // 131,072
    int lane = e & 63, nt = (e >> 6) & 3, kt = (e >> 8) & 7, nb = e >> 11;
    int q = (lane & 15) >> 2, cc = lane & 3;
    int hh = nb * 16 + nt * 4 + cc;
    int i0 = kt * 32 + (lane >> 4) * 8;
    const float* src = Wx + (size_t)q * (I_ * H_) + (size_t)i0 * H_ + hh;
    unsigned short u[8];
#pragma unroll
    for (int j = 0; j < 8; ++j) u[j] = f2bf(src[(size_t)j * H_]);
    uint4 out;
    out.x = (unsigned)u[0] | ((unsigned)u[1] << 16);
    out.y = (unsigned)u[2] | ((unsigned)u[3] << 16);
    out.z = (unsigned)u[4] | ((unsigned)u[5] << 16);
    out.w = (unsigned)u[6] | ((unsigned)u[7] << 16);
    wxp[e] = out;
}

// ---------------------------------------------------------------- persistent LSTM
// Blocks 0..63: LSTM (block nb owns h-cols [nb*16,+16), K-split across 4 waves).
// Blocks 64..255: VALU warmers. flags[nb*4+w] = # published h states.
// h ring: 4 buffers (16384 u64). Step t reads buf[t&3], writes buf[(t+1)&3].
// Per step: {Ax loads + flag PROBE} -> x-MFMAs (probe RT hides under them) ->
// check/poll -> sc1 h loads (all in flight) -> h-MFMAs -> LDS join -> gates ->
// h store -> vmcnt(0) -> relaxed flag.
__global__ __launch_bounds__(256, 1) void lstm_kernel(const unsigned short* __restrict__ xb,
                                                      const uint4* __restrict__ whp,
                                                      const uint4* __restrict__ wxp,
                                                      const float* __restrict__ bx,
                                                      const float* __restrict__ bh,
                                                      const float* __restrict__ Wp,
                                                      const float* __restrict__ bp,
                                                      unsigned short* __restrict__ hbuf,
                                                      unsigned int* __restrict__ flags,
                                                      float* __restrict__ out) {
    extern __shared__ float zpart[];     // [2][4][64][ZST] = 139,264 B (double-buffered)
    int tid = threadIdx.x, lane = tid & 63, w = tid >> 6;
    int nb = blockIdx.x;
    unsigned int* done = flags + 768;    // byte offset 3072, separate line

    if (nb >= 64) {
        // ---- warmer: dependent-FMA spin to hold the power state up
        float a = 1.0f + (float)tid * 0.001f;
        const float bm = 1.0000001f, cm = 0.9999999f;
        while (ALD32(done) == 0u) {
#pragma unroll
            for (int i = 0; i < 512; ++i) a = __builtin_fmaf(a, bm, cm);
        }
        if (__float_as_uint(a) == 0xDEADBEEFu) AST32(&flags[200], 1u);  // sink
        return;
    }

    int ma = lane & 15, quad = lane >> 4;

    // resident weight fragments (B-operands), pinned into AGPRs
    const s16x8* whpp = (const s16x8*)whp;
    const s16x8* wxpp = (const s16x8*)wxp;
    s16x8 whf[4][8], wxf[4][2];
#pragma unroll
    for (int nt = 0; nt < 4; ++nt) {
#pragma unroll
        for (int k = 0; k < 8; ++k)
            whf[nt][k] = whpp[nb * 8192 + (w * 8 + k) * 256 + nt * 64 + lane];
#pragma unroll
        for (int k = 0; k < 2; ++k)
            wxf[nt][k] = wxpp[nb * 2048 + (w * 2 + k) * 256 + nt * 64 + lane];
    }
#pragma unroll
    for (int nt = 0; nt < 4; ++nt) {
#pragma unroll
        for (int k = 0; k < 8; ++k) PIN_A(whf[nt][k]);
#pragma unroll
        for (int k = 0; k < 2; ++k) PIN_A(wxf[nt][k]);
    }

    // gate-stage ownership: thread (gb, wq) -> batch gb, h-cols nb*16+wq*4..+4
    int gb = tid >> 2, wq = tid & 3;
    float bias[4][4];
#pragma unroll
    for (int g = 0; g < 4; ++g)
#pragma unroll
        for (int i = 0; i < 4; ++i) {
            int n = g * H_ + nb * 16 + wq * 4 + i;
            bias[g][i] = bx[n] + bh[n];
        }

    u64* hbase = (u64*)hbuf;             // 4 buffers x 16384 u64

    // h(-1)=0 init into buf 0 (wave's own 512 B slice) + per-wave publish
    AST64(&hbase[nb * 256 + tid], 0ull);
    asm volatile("s_waitcnt vmcnt(0)" ::: "memory");
    if (lane == 0) AST32(&flags[nb * 4 + w], 1u);

    float cst[4] = {0.f, 0.f, 0.f, 0.f};

    for (int t = 0; t < T_; ++t) {
        // ---- x fragments + flag PROBE issued first: both in flight during x-MFMAs
        s16x8 Ax[4][2];
#pragma unroll
        for (int mt = 0; mt < 4; ++mt) {
            const unsigned short* xrow =
                xb + ((size_t)t * B_ + mt * 16 + ma) * I_ + w * 64 + quad * 8;
            Ax[mt][0] = *(const s16x8*)xrow;
            Ax[mt][1] = *(const s16x8*)(xrow + 32);
        }
        unsigned probe = ALD32(&flags[w * 64 + lane]);   // early detect load
        __builtin_amdgcn_sched_barrier(0);               // keep probe issue above MFMAs

        // ---- x-projection MFMAs (no cross-block dependence); probe RT hides here
        f32x4 acc[4][4] = {};
#pragma unroll
        for (int mt = 0; mt < 4; ++mt)
#pragma unroll
            for (int kx = 0; kx < 2; ++kx)
#pragma unroll
                for (int nt = 0; nt < 4; ++nt)
                    acc[mt][nt] = __builtin_amdgcn_mfma_f32_16x16x32_bf16(Ax[mt][kx], wxf[nt][kx],
                                                                          acc[mt][nt], 0, 0, 0);
        __builtin_amdgcn_sched_barrier(0);   // keep the x-cluster ahead of the poll

        // ---- detect: use the probe result; fall into sleep-poll only if not ready
        {
            unsigned tgt = (unsigned)(t + 1);
            if (__ballot(probe < tgt) != 0ull) {
                for (;;) {
                    __builtin_amdgcn_s_sleep(1);
                    unsigned v = ALD32(&flags[w * 64 + lane]);
                    if (__ballot(v < tgt) == 0ull) break;
                }
            }
        }

        const u64* hp = hbase + (size_t)(t & 3) * 16384;        // h(t-1)
        u64*       hn = hbase + (size_t)((t + 1) & 3) * 16384;  // h(t)

        // ---- issue ALL h loads up front: 64 x 8 B per lane in flight at once
        u64 Ah[4][16];
#pragma unroll
        for (int mt = 0; mt < 4; ++mt) {
            int row = mt * 16 + ma;
#pragma unroll
            for (int kl = 0; kl < 8; ++kl) {
                const u64* p = hp + ((size_t)((w * 8 + kl) * 2 + (quad >> 1))) * 256
                               + (size_t)row * 4 + (quad & 1) * 2;
                Ah[mt][kl * 2]     = ALD64(p);
                Ah[mt][kl * 2 + 1] = ALD64(p + 1);
            }
        }

#pragma unroll
        for (int mt = 0; mt < 4; ++mt) {
#pragma unroll
            for (int kl = 0; kl < 8; ++kl) {
                union { u64 q[2]; s16x8 v; } au;
                au.q[0] = Ah[mt][kl * 2];
                au.q[1] = Ah[mt][kl * 2 + 1];
#pragma unroll
                for (int nt = 0; nt < 4; ++nt)
                    acc[mt][nt] = __builtin_amdgcn_mfma_f32_16x16x32_bf16(au.v, whf[nt][kl],
                                                                          acc[mt][nt], 0, 0, 0);
            }
        }

        // ---- write partial to LDS (parity-selected buffer; safe under 1-barrier drift)
        float* zb = zpart + (size_t)(t & 1) * ZBUF;
        float* zp = zb + w * ZPW;
#pragma unroll
        for (int mt = 0; mt < 4; ++mt)
#pragma unroll
            for (int nt = 0; nt < 4; ++nt)
#pragma unroll
                for (int r = 0; r < 4; ++r)
                    zp[(mt * 16 + quad * 4 + r) * ZST + nt * 16 + ma] = acc[mt][nt][r];
        __syncthreads();                 // the ONLY barrier per step (partials complete)

        // ---- gates: sum 4 partials, z col = wq*16 + g*4 + i
        float zs[4][4];
#pragma unroll
        for (int g = 0; g < 4; ++g) {
            float4 s = make_float4(0.f, 0.f, 0.f, 0.f);
#pragma unroll
            for (int p = 0; p < 4; ++p) {
                float4 v = *(const float4*)(zb + p * ZPW + gb * ZST + wq * 16 + g * 4);
                s.x += v.x; s.y += v.y; s.z += v.z; s.w += v.w;
            }
            zs[g][0] = s.x; zs[g][1] = s.y; zs[g][2] = s.z; zs[g][3] = s.w;
        }
        unsigned short hh[4];
#pragma unroll
        for (int i = 0; i < 4; ++i) {
            float g  = ftanh(zs[0][i] + bias[0][i]);
            float ii = fsig (zs[1][i] + bias[1][i]);
            float ff = fsig (zs[2][i] + bias[2][i]);
            float oo = fsig (zs[3][i] + bias[3][i]);
            float c  = g * ii + cst[i] * ff;
            cst[i] = c;
            hh[i] = f2bf(ftanh(c) * oo);
        }
        u64 hv = (u64)hh[0] | ((u64)hh[1] << 16) | ((u64)hh[2] << 32) | ((u64)hh[3] << 48);
        AST64(&hn[nb * 256 + tid], hv);  // wave's own contiguous 512 B slice

        // ---- per-wave publish: own stores drained -> own flag (R1/R5 form)
        asm volatile("s_waitcnt vmcnt(0)" ::: "memory");
        if (lane == 0) AST32(&flags[nb * 4 + w], (unsigned)(t + 2));
    }

    // final wait: all 256 wave-flags at T+1
    {
        unsigned tgt = (unsigned)(T_ + 1);
        for (;;) {
            unsigned v = ALD32(&flags[w * 64 + lane]);
            if (__ballot(v < tgt) == 0ull) break;
            __builtin_amdgcn_s_sleep(1);
        }
    }
    __syncthreads();
    if (nb == 0 && tid == 0) AST32(done, 1u);   // release warmers

    // ---------------- projection + softmax: block nb handles batch row nb
    int b = nb;
    union { u64 q; unsigned short s[4]; } hu;
    hu.q = ALD64(&hbase[(tid >> 2) * 256 + b * 4 + (tid & 3)]);   // h(T-1) -> buf 0
    int j0 = (tid >> 2) * 16 + (tid & 3) * 4;
    float pacc[O_];
#pragma unroll
    for (int o = 0; o < O_; ++o) pacc[o] = 0.f;
#pragma unroll
    for (int j = 0; j < 4; ++j) {
        float hvv = bf2f(hu.s[j]);
        const float* wr = Wp + (size_t)(j0 + j) * O_;
#pragma unroll
        for (int o = 0; o < O_; ++o) pacc[o] += hvv * wr[o];
    }
    float* red = zpart;
#pragma unroll
    for (int o = 0; o < O_; ++o) red[tid * O_ + o] = pacc[o];
    __syncthreads();
    for (int s2 = 128; s2 > 0; s2 >>= 1) {
        if (tid < s2) {
#pragma unroll
            for (int o = 0; o < O_; ++o) red[tid * O_ + o] += red[(tid + s2) * O_ + o];
        }
        __syncthreads();
    }
    if (tid == 0) {
        float p[O_];
        for (int o = 0; o < O_; ++o) p[o] = red[o] + bp[o];
        float mx = p[0];
        for (int o = 1; o < O_; ++o) mx = fmaxf(mx, p[o]);
        float e[O_], sum = 0.f;
        for (int o = 0; o < O_; ++o) { e[o] = __expf(p[o] - mx); sum += e[o]; }
        float inv = 1.f / sum;
        for (int o = 0; o < O_; ++o) out[b * O_ + o] = e[o] * inv;
    }
}

// ---------------------------------------------------------------- launch
extern "C" void kernel_launch(void* const* d_in, const int* in_sizes, int n_in,
                              void* d_out, int out_size, void* d_ws, size_t ws_size,
                              hipStream_t stream) {
    (void)in_sizes; (void)n_in; (void)out_size; (void)ws_size;
    const float* x  = (const float*)d_in[0];
    const float* Wx = (const float*)d_in[1];
    const float* bx = (const float*)d_in[2];
    const float* Wh = (const float*)d_in[3];
    const float* bh = (const float*)d_in[4];
    const float* Wp = (const float*)d_in[5];
    const float* bp = (const float*)d_in[6];

    const size_t xbB  = (size_t)T_ * B_ * I_ * 2;      // 16 MB
    const size_t whpB = (size_t)4 * H_ * H_ * 2;       // 8 MB
    const size_t wxpB = (size_t)4 * I_ * H_ * 2;       // 2 MB
    const size_t hB   = (size_t)4 * B_ * H_ * 2;       // 512 KB (4-deep ring)

    char* ws = (char*)d_ws;
    unsigned short* xb    = (unsigned short*)ws;
    uint4*          whp   = (uint4*)(ws + xbB);
    uint4*          wxp   = (uint4*)(ws + xbB + whpB);
    unsigned short* hbuf  = (unsigned short*)(ws + xbB + whpB + wxpB);
    unsigned int*   flags = (unsigned int*)(ws + xbB + whpB + wxpB + hB);

    static bool attr_set = false;
    if (!attr_set) {
        (void)hipFuncSetAttribute((const void*)lstm_kernel,
                                  hipFuncAttributeMaxDynamicSharedMemorySize, LDS_ALLOC);
        attr_set = true;
    }

    hipError_t e0 = hipMemsetAsync(flags, 0, 4096, stream);
    (void)e0;
    cast_xT_kernel<<<8192, 256, 0, stream>>>(x, xb);
    pack_wh_kernel<<<2048, 256, 0, stream>>>(Wh, whp);
    pack_wx_kernel<<< 512, 256, 0, stream>>>(Wx, wxp);
    lstm_kernel<<<64 + 192, 256, LDS_ALLOC, stream>>>(xb, whp, wxp, bx, bh, Wp, bp, hbuf, flags,
                                                      (float*)d_out);
}